// Round 4
// baseline (407.590 us; speedup 1.0000x reference)
//
#include <hip/hip_runtime.h>
#include <math.h>

// Problem constants (B=2, C=48, HEADS=3, H=W=64)
#define NPIX 4096     // H*W
#define SPLIT 8       // spatial-attn m-splits
#define TM 128        // m-tile staged in LDS

// Workspace layout (float offsets); total 6,494,976 floats ~= 26 MB
//  t_buf   @ 0        [B][144][N]   conv1x1(LN(inp)) pre-dwconv
//  qkvb    @ 1179648  [B][144][N]   post-dwconv q/k/v
//  outc    @ 2359296  [B][48][N]    channel-attn output
//  y_ws    @ 2752512  [B][48][N]    post-attn residual y
//  spl_o   @ 3145728  [6][8][16][N] spatial-attn partial O
//  spl_l   @ 6291456  [6][8][N]     spatial-attn partial l
//  cd_norm @ 6488064  [6][4][32]    chattn partial row-norms (q rows 0-15, k 16-31)
//  cd_dot  @ 6488832  [6][4][16][16] chattn partial q.k dots

// ---------------- LN1 + qkv conv1x1 ----------------
// grid: B*(N/64)*4 (o-split 4), block 64. Column of 48 channels kept in regs.
__global__ __launch_bounds__(64) void ln_qkv_kernel(
    const float* __restrict__ inp, const float* __restrict__ qkv_w,
    const float* __restrict__ qkv_b, const float* __restrict__ ln1_w,
    const float* __restrict__ ln1_b, float* __restrict__ t_buf)
{
  int bid = blockIdx.x;
  int os = bid & 3; bid >>= 2;
  int b = bid >> 6;
  int n = ((bid & 63) << 6) + threadIdx.x;
  const float* src = inp + (size_t)b * 48 * NPIX;
  float x[48];
  float mu = 0.f;
#pragma unroll
  for (int c = 0; c < 48; c++) { x[c] = src[c * NPIX + n]; mu += x[c]; }
  mu *= (1.f / 48.f);
  float var = 0.f;
#pragma unroll
  for (int c = 0; c < 48; c++) { float d = x[c] - mu; var += d * d; }
  var *= (1.f / 48.f);
  float rstd = 1.f / sqrtf(var + 1e-6f);
#pragma unroll
  for (int c = 0; c < 48; c++) x[c] = (x[c] - mu) * rstd * ln1_w[c] + ln1_b[c];
  float* dst = t_buf + (size_t)b * 144 * NPIX + n;
  for (int o = os * 36; o < os * 36 + 36; o++) {
    const float* wr = qkv_w + o * 48;
    float a0 = 0.f, a1 = 0.f;
#pragma unroll
    for (int c = 0; c < 48; c += 2) { a0 += wr[c] * x[c]; a1 += wr[c + 1] * x[c + 1]; }
    dst[(size_t)o * NPIX] = a0 + a1 + qkv_b[o];
  }
}

// ---------------- depthwise 3x3 + bias ----------------
// thread per (b,ch,pixel); grid 2*144*4096/256
__global__ __launch_bounds__(256) void dwconv_kernel(
    const float* __restrict__ t_buf, const float* __restrict__ dw_w,
    const float* __restrict__ dw_b, float* __restrict__ qkvb)
{
  int gid = blockIdx.x * 256 + threadIdx.x;
  int n = gid & (NPIX - 1);
  int bc = gid >> 12;           // 0..287
  int ch = bc % 144;
  int i = n >> 6, j = n & 63;
  const float* src = t_buf + (size_t)bc * NPIX;
  float acc = dw_b[ch];
#pragma unroll
  for (int di = 0; di < 3; di++) {
    int ii = i + di - 1;
    if (ii < 0 || ii > 63) continue;
#pragma unroll
    for (int dj = 0; dj < 3; dj++) {
      int jj = j + dj - 1;
      if (jj < 0 || jj > 63) continue;
      acc += src[ii * 64 + jj] * dw_w[ch * 9 + di * 3 + dj];
    }
  }
  qkvb[(size_t)bc * NPIX + n] = acc;
}

// ---------------- channel attention, stage A: partial norms + dots ----------------
// grid: 6 bh * 4 n-chunks = 24 blocks, 1024 threads
__global__ __launch_bounds__(1024) void chattn_dots_kernel(
    const float* __restrict__ qkv, float* __restrict__ cd_norm,
    float* __restrict__ cd_dot)
{
  int bid = blockIdx.x;
  int nc = bid & 3, bh = bid >> 2;
  int b = bh / 3, h = bh % 3;
  int tid = threadIdx.x;
  const float* q = qkv + (size_t)(b * 144 + h * 16) * NPIX;
  const float* k = qkv + (size_t)(b * 144 + 48 + h * 16) * NPIX;

  __shared__ float part[32][33];
  __shared__ float att4[16][16][4];

  // row-norm partials: r = 0..31 (q rows 0-15, k rows 16-31), 32 partials of 32
  {
    int r = tid >> 5, pp = tid & 31;
    const float* s2 = ((r < 16) ? (q + r * NPIX) : (k + (r - 16) * NPIX))
                    + nc * 1024 + pp * 32;
    float ss = 0.f;
#pragma unroll
    for (int i = 0; i < 32; i += 4) {
      float4 xx = *(const float4*)(s2 + i);
      ss += xx.x * xx.x + xx.y * xx.y + xx.z * xx.z + xx.w * xx.w;
    }
    part[r][pp] = ss;
  }
  // dot partials: (c,d) over this chunk, 4-way sub-split
  {
    int c = tid >> 6, d = (tid >> 2) & 15, pt = tid & 3;
    const float* qc = q + c * NPIX + nc * 1024 + pt * 256;
    const float* kd = k + d * NPIX + nc * 1024 + pt * 256;
    float acc = 0.f;
    for (int n2 = 0; n2 < 256; n2 += 4) {
      float4 xq = *(const float4*)(qc + n2);
      float4 xk = *(const float4*)(kd + n2);
      acc += xq.x * xk.x + xq.y * xk.y + xq.z * xk.z + xq.w * xk.w;
    }
    att4[c][d][pt] = acc;
  }
  __syncthreads();
  if (tid < 32) {
    float ss = 0.f;
#pragma unroll
    for (int pp = 0; pp < 32; pp++) ss += part[tid][pp];
    cd_norm[(size_t)(bh * 4 + nc) * 32 + tid] = ss;
  }
  if (tid < 256) {
    int cc = tid >> 4, dd = tid & 15;
    cd_dot[((size_t)(bh * 4 + nc) * 16 + cc) * 16 + dd] =
        att4[cc][dd][0] + att4[cc][dd][1] + att4[cc][dd][2] + att4[cc][dd][3];
  }
}

// ---------------- channel attention, stage B: softmax + PV ----------------
// grid: 6 bh * 16 n-slices = 96 blocks, 256 threads (n-slice of 256 pixels)
__global__ __launch_bounds__(256) void chattn_pv_kernel(
    const float* __restrict__ qkv, const float* __restrict__ cd_norm,
    const float* __restrict__ cd_dot, const float* __restrict__ temp1,
    float* __restrict__ outc)
{
  int bid = blockIdx.x;
  int ns = bid & 15, bh = bid >> 4;
  int b = bh / 3, h = bh % 3;
  int tid = threadIdx.x;
  const float* v = qkv + (size_t)(b * 144 + 96 + h * 16) * NPIX;

  __shared__ float fac[32];
  __shared__ float atte[16][17];
  __shared__ float att[16][17];

  if (tid < 32) {
    float ss = 0.f;
#pragma unroll
    for (int nc = 0; nc < 4; nc++) ss += cd_norm[(size_t)(bh * 4 + nc) * 32 + tid];
    fac[tid] = 1.f / fmaxf(sqrtf(ss), 1e-12f);
  }
  __syncthreads();
  int cc = tid >> 4, dd = tid & 15;
  float t1 = temp1[h];
  if (tid < 256) {
    float a = 0.f;
#pragma unroll
    for (int nc = 0; nc < 4; nc++)
      a += cd_dot[((size_t)(bh * 4 + nc) * 16 + cc) * 16 + dd];
    float z = fmaxf(a * fac[cc] * fac[16 + dd] * t1, 0.f);
    atte[cc][dd] = __expf(z);
  }
  __syncthreads();
  if (tid < 256) {
    float rs = 0.f;
#pragma unroll
    for (int d2 = 0; d2 < 16; d2++) rs += atte[cc][d2];
    att[cc][dd] = atte[cc][dd] / rs;
  }
  __syncthreads();

  // PV over this block's 256-pixel slice
  int n2 = ns * 256 + tid;
  float vv[16];
#pragma unroll
  for (int d2 = 0; d2 < 16; d2++) vv[d2] = v[d2 * NPIX + n2];
#pragma unroll
  for (int c2 = 0; c2 < 16; c2++) {
    float a = 0.f;
#pragma unroll
    for (int d2 = 0; d2 < 16; d2++) a += att[c2][d2] * vv[d2];
    outc[(size_t)(b * 48 + h * 16 + c2) * NPIX + n2] = a;
  }
}

// ---------------- spatial attention (flash, no-max since z in [0,|temp2|]) ----------------
// grid: 6 * SPLIT * 32 qtiles = 1536 blocks, 64 threads, 2 queries/thread.
// qt in LOW grid bits: the 32 consecutively-dispatched blocks share one (bh,s)
// K/V m-range -> L2-local staging reads.
// q/k l2-normalization fused in (q per-thread in regs; k rows in LDS — thread
// tid stages ALL 16 elems of rows tid and tid+64 itself, so it can normalize
// its own rows without a barrier).
__global__ __launch_bounds__(64) void spattn_kernel(
    const float* __restrict__ qkv, const float* __restrict__ temp2,
    float* __restrict__ spl_o, float* __restrict__ spl_l)
{
  int bid = blockIdx.x;
  int qt = bid & 31;
  int s = (bid >> 5) & 7;
  int bh = bid >> 8;             // 0..5
  int b = bh / 3, h = bh % 3;
  int tid = threadIdx.x;
  float t2 = temp2[h];

  const float* Q = qkv + (size_t)(b * 144 + h * 16) * NPIX;
  const float* K = qkv + (size_t)(b * 144 + 48 + h * 16) * NPIX;
  const float* V = qkv + (size_t)(b * 144 + 96 + h * 16) * NPIX;

  int q0 = qt * 128;
  int qa_i = q0 + tid, qb_i = q0 + 64 + tid;

  float qa[16], qb[16], oa[16], ob[16];
  float ssa = 0.f, ssb = 0.f;
#pragma unroll
  for (int c = 0; c < 16; c++) {
    qa[c] = Q[c * NPIX + qa_i];
    qb[c] = Q[c * NPIX + qb_i];
    ssa += qa[c] * qa[c]; ssb += qb[c] * qb[c];
    oa[c] = 0.f; ob[c] = 0.f;
  }
  {
    float fa = 1.f / fmaxf(sqrtf(ssa), 1e-12f);
    float fb = 1.f / fmaxf(sqrtf(ssb), 1e-12f);
#pragma unroll
    for (int c = 0; c < 16; c++) { qa[c] *= fa; qb[c] *= fb; }
  }
  float la = 0.f, lb = 0.f;

  __shared__ float Kt[TM][20];   // rows 80B -> 16B aligned for b128 reads
  __shared__ float Vt[TM][20];

  int mbase = s * (NPIX / SPLIT);
  for (int t = 0; t < (NPIX / SPLIT) / TM; t++) {
    int m0 = mbase + t * TM;
    __syncthreads();             // protect prev tile's readers
    for (int idx = tid; idx < 16 * TM; idx += 64) {
      int c = idx >> 7, mm = idx & (TM - 1);   // mm == tid or tid+64
      Kt[mm][c] = K[c * NPIX + m0 + mm];
      Vt[mm][c] = V[c * NPIX + m0 + mm];
    }
    // normalize own K rows (tid, tid+64) — own LDS writes visible to self
#pragma unroll
    for (int rr = 0; rr < 2; rr++) {
      int r = tid + rr * 64;
      float kk[16];
      ((float4*)kk)[0] = ((const float4*)&Kt[r][0])[0];
      ((float4*)kk)[1] = ((const float4*)&Kt[r][0])[1];
      ((float4*)kk)[2] = ((const float4*)&Kt[r][0])[2];
      ((float4*)kk)[3] = ((const float4*)&Kt[r][0])[3];
      float ss = 0.f;
#pragma unroll
      for (int c = 0; c < 16; c++) ss += kk[c] * kk[c];
      float fc = 1.f / fmaxf(sqrtf(ss), 1e-12f);
#pragma unroll
      for (int c = 0; c < 16; c++) kk[c] *= fc;
      ((float4*)&Kt[r][0])[0] = ((float4*)kk)[0];
      ((float4*)&Kt[r][0])[1] = ((float4*)kk)[1];
      ((float4*)&Kt[r][0])[2] = ((float4*)kk)[2];
      ((float4*)&Kt[r][0])[3] = ((float4*)kk)[3];
    }
    __syncthreads();
#pragma unroll 2
    for (int mm = 0; mm < TM; mm++) {
      const float4* kr = (const float4*)(&Kt[mm][0]);
      float ka[16];
      ((float4*)ka)[0] = kr[0]; ((float4*)ka)[1] = kr[1];
      ((float4*)ka)[2] = kr[2]; ((float4*)ka)[3] = kr[3];
      float sa = 0.f, sb = 0.f;
#pragma unroll
      for (int c = 0; c < 16; c++) { sa += qa[c] * ka[c]; sb += qb[c] * ka[c]; }
      float ea = __expf(fmaxf(sa * t2, 0.f));
      float eb = __expf(fmaxf(sb * t2, 0.f));
      la += ea; lb += eb;
      const float4* vr = (const float4*)(&Vt[mm][0]);
      float va[16];
      ((float4*)va)[0] = vr[0]; ((float4*)va)[1] = vr[1];
      ((float4*)va)[2] = vr[2]; ((float4*)va)[3] = vr[3];
#pragma unroll
      for (int c = 0; c < 16; c++) { oa[c] += ea * va[c]; ob[c] += eb * va[c]; }
    }
  }

  size_t base = ((size_t)bh * SPLIT + s);
#pragma unroll
  for (int c = 0; c < 16; c++) {
    spl_o[(base * 16 + c) * NPIX + qa_i] = oa[c];
    spl_o[(base * 16 + c) * NPIX + qb_i] = ob[c];
  }
  spl_l[base * NPIX + qa_i] = la;
  spl_l[base * NPIX + qb_i] = lb;
}

// ---------------- combine spatial partials + project outc/outs + residual -> y ----------------
// grid: B*(N/64)*2 (o-split 2), block 64
__global__ __launch_bounds__(64) void proj_kernel(
    const float* __restrict__ inp, const float* __restrict__ outc,
    const float* __restrict__ spl_o, const float* __restrict__ spl_l,
    const float* __restrict__ po1_w, const float* __restrict__ po1_b,
    const float* __restrict__ po2_w, const float* __restrict__ po2_b,
    const float* __restrict__ beta, const float* __restrict__ beta2,
    float* __restrict__ y_ws)
{
  int bid = blockIdx.x;
  int os = bid & 1; bid >>= 1;
  int b = bid >> 6;
  int n = ((bid & 63) << 6) + threadIdx.x;

  // reduce spatial partials: ov[c] = (sum_s spl_o) / (sum_s spl_l per head)
  float ov[48];
#pragma unroll
  for (int c = 0; c < 48; c++) ov[c] = 0.f;
  float lsum[3] = {0.f, 0.f, 0.f};
  for (int s = 0; s < SPLIT; s++) {
#pragma unroll
    for (int hh = 0; hh < 3; hh++)
      lsum[hh] += spl_l[((size_t)((b * 3 + hh) * SPLIT) + s) * NPIX + n];
#pragma unroll
    for (int c = 0; c < 48; c++) {
      int hh = c >> 4, cc = c & 15;
      ov[c] += spl_o[((((size_t)(b * 3 + hh) * SPLIT + s) * 16) + cc) * NPIX + n];
    }
  }
#pragma unroll
  for (int c = 0; c < 48; c++) ov[c] *= 1.f / lsum[c >> 4];

  float oc[48];
  const float* pc = outc + (size_t)b * 48 * NPIX;
#pragma unroll
  for (int c = 0; c < 48; c++) oc[c] = pc[c * NPIX + n];

  for (int o = os * 24; o < os * 24 + 24; o++) {
    const float* w1 = po1_w + o * 48;
    const float* w2 = po2_w + o * 48;
    float a1 = 0.f, a2 = 0.f;
#pragma unroll
    for (int c = 0; c < 48; c++) { a1 += w1[c] * oc[c]; a2 += w2[c] * ov[c]; }
    float yv = inp[(size_t)(b * 48 + o) * NPIX + n]
             + (a1 + po1_b[o]) * beta[o] + (a2 + po2_b[o]) * beta2[o];
    y_ws[(size_t)(b * 48 + o) * NPIX + n] = yv;
  }
}

// ---------------- LN2 + GLU FFN + residual -> out ----------------
// grid: B*(N/32) = 256 blocks, 128 threads: 32 pixels x 4 j-groups (split-j
// over the 48 gate channels, LDS reduce; pad 49 kills the stride-48 bank clash)
__global__ __launch_bounds__(128) void ffn_kernel(
    const float* __restrict__ y_ws, const float* __restrict__ conv4_w,
    const float* __restrict__ conv4_b, const float* __restrict__ conv5_w,
    const float* __restrict__ conv5_b, const float* __restrict__ ln2_w,
    const float* __restrict__ ln2_b, const float* __restrict__ gamma,
    float* __restrict__ outp)
{
  int bid = blockIdx.x;
  int b = bid >> 7;
  int n0 = (bid & 127) << 5;
  int tid = threadIdx.x;
  int p = tid & 31, jg = tid >> 5;   // pixel-in-tile, j-group 0..3
  int n = n0 + p;
  const float* src = y_ws + (size_t)b * 48 * NPIX;

  // LN2 (recomputed per j-group; loads are cache hits)
  float t[48];
  float mu = 0.f;
#pragma unroll
  for (int c = 0; c < 48; c++) { t[c] = src[c * NPIX + n]; mu += t[c]; }
  mu *= (1.f / 48.f);
  float var = 0.f;
#pragma unroll
  for (int c = 0; c < 48; c++) { float d = t[c] - mu; var += d * d; }
  var *= (1.f / 48.f);
  float rstd = 1.f / sqrtf(var + 1e-6f);
#pragma unroll
  for (int c = 0; c < 48; c++) t[c] = (t[c] - mu) * rstd * ln2_w[c] + ln2_b[c];

  float fa[48];
#pragma unroll
  for (int o = 0; o < 48; o++) fa[o] = 0.f;
  for (int j = jg * 12; j < jg * 12 + 12; j++) {
    const float* w4a = conv4_w + j * 48;
    const float* w4b = conv4_w + (j + 48) * 48;
    float g1 = conv4_b[j], g2 = conv4_b[j + 48];
#pragma unroll
    for (int c = 0; c < 48; c++) { g1 += w4a[c] * t[c]; g2 += w4b[c] * t[c]; }
    float hh = g1 * g2;
#pragma unroll
    for (int o = 0; o < 48; o++) fa[o] += conv5_w[o * 48 + j] * hh;
  }

  __shared__ float part[4][32][49];   // ~24.5 KiB, stride 49 = conflict-free
#pragma unroll
  for (int o = 0; o < 48; o++) part[jg][p][o] = fa[o];
  __syncthreads();
  // all 128 threads: group jg writes outputs o = jg*12 .. jg*12+11 at pixel p
#pragma unroll
  for (int oo = 0; oo < 12; oo++) {
    int o = jg * 12 + oo;
    float sum = part[0][p][o] + part[1][p][o] + part[2][p][o] + part[3][p][o];
    outp[(size_t)(b * 48 + o) * NPIX + n] =
        src[o * NPIX + n] + (sum + conv5_b[o]) * gamma[o];
  }
}

extern "C" void kernel_launch(void* const* d_in, const int* in_sizes, int n_in,
                              void* d_out, int out_size, void* d_ws, size_t ws_size,
                              hipStream_t stream)
{
  (void)in_sizes; (void)n_in; (void)out_size; (void)ws_size;
  const float* inp     = (const float*)d_in[0];
  const float* qkv_w   = (const float*)d_in[1];
  const float* qkv_b   = (const float*)d_in[2];
  const float* dw_w    = (const float*)d_in[3];
  const float* dw_b    = (const float*)d_in[4];
  const float* po1_w   = (const float*)d_in[5];
  const float* po1_b   = (const float*)d_in[6];
  const float* po2_w   = (const float*)d_in[7];
  const float* po2_b   = (const float*)d_in[8];
  const float* temp1   = (const float*)d_in[9];
  const float* temp2   = (const float*)d_in[10];
  const float* conv4_w = (const float*)d_in[11];
  const float* conv4_b = (const float*)d_in[12];
  const float* conv5_w = (const float*)d_in[13];
  const float* conv5_b = (const float*)d_in[14];
  const float* ln1_w   = (const float*)d_in[15];
  const float* ln1_b   = (const float*)d_in[16];
  const float* ln2_w   = (const float*)d_in[17];
  const float* ln2_b   = (const float*)d_in[18];
  const float* beta    = (const float*)d_in[19];
  const float* beta2   = (const float*)d_in[20];
  const float* gamma   = (const float*)d_in[21];
  float* out = (float*)d_out;

  float* ws      = (float*)d_ws;
  float* t_buf   = ws;
  float* qkvb    = ws + 1179648;
  float* outc    = ws + 2359296;
  float* y_ws    = ws + 2752512;
  float* spl_o   = ws + 3145728;
  float* spl_l   = ws + 6291456;
  float* cd_norm = ws + 6488064;
  float* cd_dot  = ws + 6488832;
  // total ws use: 6,494,976 floats (~26 MB)

  // 1) LN1 + qkv 1x1 conv
  ln_qkv_kernel<<<2 * 64 * 4, 64, 0, stream>>>(inp, qkv_w, qkv_b, ln1_w, ln1_b, t_buf);
  // 2) depthwise 3x3
  dwconv_kernel<<<(2 * 144 * NPIX) / 256, 256, 0, stream>>>(t_buf, dw_w, dw_b, qkvb);
  // 3a) channel attention: partial norms + dots (24 blocks)
  chattn_dots_kernel<<<24, 1024, 0, stream>>>(qkvb, cd_norm, cd_dot);
  // 3b) channel attention: softmax + PV (96 blocks)
  chattn_pv_kernel<<<96, 256, 0, stream>>>(qkvb, cd_norm, cd_dot, temp1, outc);
  // 4) spatial attention (flash, split-m, fused q/k l2-norm)
  spattn_kernel<<<6 * 32 * SPLIT, 64, 0, stream>>>(qkvb, temp2, spl_o, spl_l);
  // 5) combine partials + output projections + residual
  proj_kernel<<<2 * 64 * 2, 64, 0, stream>>>(inp, outc, spl_o, spl_l,
                                             po1_w, po1_b, po2_w, po2_b,
                                             beta, beta2, y_ws);
  // 6) LN2 + GLU FFN + residual
  ffn_kernel<<<2 * 128, 128, 0, stream>>>(y_ws, conv4_w, conv4_b, conv5_w, conv5_b,
                                          ln2_w, ln2_b, gamma, out);
}

// Round 7
// 313.701 us; speedup vs baseline: 1.2993x; 1.2993x over previous
//
#include <hip/hip_runtime.h>
#include <math.h>

// Problem constants (B=2, C=48, HEADS=3, H=W=64)
#define NPIX 4096     // H*W
#define SPLIT 8       // spatial-attn m-splits
#define TM 64         // m-tile staged in LDS (64 -> 10 KiB/block -> 16 blocks/CU LDS cap)

// Workspace layout (float offsets); total 6,291,456 floats = 25.2 MB
// (spl_l / cd_* / outs overlay the dead t_buf region — t_buf's last reader
//  is dwconv, and all overlay writers run after dwconv)
//  t_buf   @ 0        [B][144][N]    conv1x1(LN(inp)) pre-dwconv  (dead after dwconv)
//    spl_l   @ 0       [6][8][N]     spatial-attn partial l
//    cd_norm @ 196608  [6][32][32]   chattn partial row-norms
//    cd_dot  @ 202752  [6][32][16][16] chattn partial q.k dots
//    outs    @ 251904  [B][48][N]    combined spatial-attn output (ends 645,120 < 1,179,648)
//  qkvb    @ 1179648  [B][144][N]    post-dwconv q/k/v
//  outc    @ 2359296  [B][48][N]     channel-attn output
//  y_ws    @ 2752512  [B][48][N]     post-attn residual y
//  spl_o   @ 3145728  [6][8][16][N]  spatial-attn partial O

typedef float f2 __attribute__((ext_vector_type(2)));

// packed fp32 FMA: d = a*b + c on both halves (full-rate on CDNA)
static __device__ __forceinline__ f2 pk_fma(f2 a, f2 b, f2 c) {
  f2 d;
  asm("v_pk_fma_f32 %0, %1, %2, %3" : "=v"(d) : "v"(a), "v"(b), "v"(c));
  return d;
}

// ---------------- LN1 + qkv conv1x1 ----------------
// grid: B*(N/64)*8 (o-split 8) = 1024 blocks, block 64.
__global__ __launch_bounds__(64) void ln_qkv_kernel(
    const float* __restrict__ inp, const float* __restrict__ qkv_w,
    const float* __restrict__ qkv_b, const float* __restrict__ ln1_w,
    const float* __restrict__ ln1_b, float* __restrict__ t_buf)
{
  int bid = blockIdx.x;
  int os = bid & 7; bid >>= 3;
  int b = bid >> 6;
  int n = ((bid & 63) << 6) + threadIdx.x;
  const float* src = inp + (size_t)b * 48 * NPIX;
  float x[48];
  float mu = 0.f;
#pragma unroll
  for (int c = 0; c < 48; c++) { x[c] = src[c * NPIX + n]; mu += x[c]; }
  mu *= (1.f / 48.f);
  float var = 0.f;
#pragma unroll
  for (int c = 0; c < 48; c++) { float d = x[c] - mu; var += d * d; }
  var *= (1.f / 48.f);
  float rstd = 1.f / sqrtf(var + 1e-6f);
#pragma unroll
  for (int c = 0; c < 48; c++) x[c] = (x[c] - mu) * rstd * ln1_w[c] + ln1_b[c];
  float* dst = t_buf + (size_t)b * 144 * NPIX + n;
  for (int o = os * 18; o < os * 18 + 18; o++) {
    const float* wr = qkv_w + o * 48;
    float a0 = 0.f, a1 = 0.f;
#pragma unroll
    for (int c = 0; c < 48; c += 2) { a0 += wr[c] * x[c]; a1 += wr[c + 1] * x[c + 1]; }
    dst[(size_t)o * NPIX] = a0 + a1 + qkv_b[o];
  }
}

// ---------------- depthwise 3x3 + bias ----------------
// thread per (b,ch,pixel); grid 2*144*4096/256 = 4608
__global__ __launch_bounds__(256) void dwconv_kernel(
    const float* __restrict__ t_buf, const float* __restrict__ dw_w,
    const float* __restrict__ dw_b, float* __restrict__ qkvb)
{
  int gid = blockIdx.x * 256 + threadIdx.x;
  int n = gid & (NPIX - 1);
  int bc = gid >> 12;           // 0..287
  int ch = bc % 144;
  int i = n >> 6, j = n & 63;
  const float* src = t_buf + (size_t)bc * NPIX;
  float acc = dw_b[ch];
#pragma unroll
  for (int di = 0; di < 3; di++) {
    int ii = i + di - 1;
    if (ii < 0 || ii > 63) continue;
#pragma unroll
    for (int dj = 0; dj < 3; dj++) {
      int jj = j + dj - 1;
      if (jj < 0 || jj > 63) continue;
      acc += src[ii * 64 + jj] * dw_w[ch * 9 + di * 3 + dj];
    }
  }
  qkvb[(size_t)bc * NPIX + n] = acc;
}

// ---------------- channel attention, stage A: partial norms + dots ----------------
// grid: 6 bh * 32 n-chunks = 192 blocks, 256 threads; chunk = 128 pixels.
// Each thread owns ONE (c,d) dot over the whole chunk (no LDS reduce needed).
__global__ __launch_bounds__(256) void chattn_dots_kernel(
    const float* __restrict__ qkv, float* __restrict__ cd_norm,
    float* __restrict__ cd_dot)
{
  int bid = blockIdx.x;
  int nc = bid & 31, bh = bid >> 5;
  int b = bh / 3, h = bh % 3;
  int tid = threadIdx.x;
  const float* q = qkv + (size_t)(b * 144 + h * 16) * NPIX;
  const float* k = qkv + (size_t)(b * 144 + 48 + h * 16) * NPIX;

  __shared__ float part[32][9];

  // row-norm partials: r = 0..31 (q rows 0-15, k rows 16-31), 8 partials of 16
  {
    int r = tid >> 3, pp = tid & 7;
    const float* s2 = ((r < 16) ? (q + r * NPIX) : (k + (r - 16) * NPIX))
                    + nc * 128 + pp * 16;
    float ss = 0.f;
#pragma unroll
    for (int i = 0; i < 16; i += 4) {
      float4 xx = *(const float4*)(s2 + i);
      ss += xx.x * xx.x + xx.y * xx.y + xx.z * xx.z + xx.w * xx.w;
    }
    part[r][pp] = ss;
  }
  // dot: thread (c,d) over this 128-pixel chunk
  int c = tid >> 4, d = tid & 15;
  const float* qc = q + c * NPIX + nc * 128;
  const float* kd = k + d * NPIX + nc * 128;
  float acc = 0.f;
  for (int i = 0; i < 128; i += 4) {
    float4 xq = *(const float4*)(qc + i);
    float4 xk = *(const float4*)(kd + i);
    acc += xq.x * xk.x + xq.y * xk.y + xq.z * xk.z + xq.w * xk.w;
  }
  __syncthreads();
  if (tid < 32) {
    float ss = 0.f;
#pragma unroll
    for (int pp = 0; pp < 8; pp++) ss += part[tid][pp];
    cd_norm[(size_t)(bh * 32 + nc) * 32 + tid] = ss;
  }
  cd_dot[((size_t)(bh * 32 + nc) * 16 + c) * 16 + d] = acc;
}

// ---------------- channel attention, stage B: softmax + PV ----------------
// grid: 6 bh * 16 n-slices = 96 blocks, 256 threads (n-slice of 256 pixels)
__global__ __launch_bounds__(256) void chattn_pv_kernel(
    const float* __restrict__ qkv, const float* __restrict__ cd_norm,
    const float* __restrict__ cd_dot, const float* __restrict__ temp1,
    float* __restrict__ outc)
{
  int bid = blockIdx.x;
  int ns = bid & 15, bh = bid >> 4;
  int b = bh / 3, h = bh % 3;
  int tid = threadIdx.x;
  const float* v = qkv + (size_t)(b * 144 + 96 + h * 16) * NPIX;

  __shared__ float fac[32];
  __shared__ float atte[16][17];
  __shared__ float att[16][17];

  if (tid < 32) {
    float ss = 0.f;
#pragma unroll
    for (int nc = 0; nc < 32; nc++) ss += cd_norm[(size_t)(bh * 32 + nc) * 32 + tid];
    fac[tid] = 1.f / fmaxf(sqrtf(ss), 1e-12f);
  }
  __syncthreads();
  int cc = tid >> 4, dd = tid & 15;
  float t1 = temp1[h];
  if (tid < 256) {
    float a = 0.f;
#pragma unroll
    for (int nc = 0; nc < 32; nc++)
      a += cd_dot[((size_t)(bh * 32 + nc) * 16 + cc) * 16 + dd];
    float z = fmaxf(a * fac[cc] * fac[16 + dd] * t1, 0.f);
    atte[cc][dd] = __expf(z);
  }
  __syncthreads();
  if (tid < 256) {
    float rs = 0.f;
#pragma unroll
    for (int d2 = 0; d2 < 16; d2++) rs += atte[cc][d2];
    att[cc][dd] = atte[cc][dd] / rs;
  }
  __syncthreads();

  // PV over this block's 256-pixel slice
  int n2 = ns * 256 + tid;
  float vv[16];
#pragma unroll
  for (int d2 = 0; d2 < 16; d2++) vv[d2] = v[d2 * NPIX + n2];
#pragma unroll
  for (int c2 = 0; c2 < 16; c2++) {
    float a = 0.f;
#pragma unroll
    for (int d2 = 0; d2 < 16; d2++) a += att[c2][d2] * vv[d2];
    outc[(size_t)(b * 48 + h * 16 + c2) * NPIX + n2] = a;
  }
}

// ---------------- spatial attention (flash, no-max since z in [0,|temp2|]) ----------------
// grid: 6 * SPLIT * 64 qtiles = 3072 blocks (12/CU, LDS cap 16/CU -> fully
// resident), 64 threads, 1 query/thread. Packed fp32 (v_pk_fma_f32) for QK
// dot and PV accumulate. K/V LDS reads are wave-broadcast -> conflict-free.
// qt in LOW grid bits: consecutively-dispatched blocks share one (bh,s)
// K/V m-range -> L2-local staging reads.
// TM=64: thread tid stages and self-normalizes exactly row tid (mm==tid
// always in the staging loop), so no barrier between stage and normalize.
__global__ __launch_bounds__(64) void spattn_kernel(
    const float* __restrict__ qkv, const float* __restrict__ temp2,
    float* __restrict__ spl_o, float* __restrict__ spl_l)
{
  int bid = blockIdx.x;
  int qt = bid & 63;
  int s = (bid >> 6) & 7;
  int bh = bid >> 9;             // 0..5
  int b = bh / 3, h = bh % 3;
  int tid = threadIdx.x;
  float t2 = temp2[h];

  const float* Q = qkv + (size_t)(b * 144 + h * 16) * NPIX;
  const float* K = qkv + (size_t)(b * 144 + 48 + h * 16) * NPIX;
  const float* V = qkv + (size_t)(b * 144 + 96 + h * 16) * NPIX;

  int qi = qt * 64 + tid;

  // load + l2-normalize own query, packed into f2 pairs
  float qv[16];
  float ssq = 0.f;
#pragma unroll
  for (int c = 0; c < 16; c++) { qv[c] = Q[c * NPIX + qi]; ssq += qv[c] * qv[c]; }
  float fq = 1.f / fmaxf(sqrtf(ssq), 1e-12f);
  f2 q2[8], o2[8];
#pragma unroll
  for (int i = 0; i < 8; i++) {
    q2[i] = (f2){qv[2 * i] * fq, qv[2 * i + 1] * fq};
    o2[i] = (f2){0.f, 0.f};
  }
  float la = 0.f;

  __shared__ float Kt[TM][20];   // rows 80B -> 16B aligned for b128 reads
  __shared__ float Vt[TM][20];

  int mbase = s * (NPIX / SPLIT);
  for (int t = 0; t < (NPIX / SPLIT) / TM; t++) {
    int m0 = mbase + t * TM;
    __syncthreads();             // protect prev tile's readers
#pragma unroll
    for (int c = 0; c < 16; c++) {
      Kt[tid][c] = K[c * NPIX + m0 + tid];
      Vt[tid][c] = V[c * NPIX + m0 + tid];
    }
    // normalize own K row (row tid) — own LDS writes visible to self
    {
      float kk[16];
      ((float4*)kk)[0] = ((const float4*)&Kt[tid][0])[0];
      ((float4*)kk)[1] = ((const float4*)&Kt[tid][0])[1];
      ((float4*)kk)[2] = ((const float4*)&Kt[tid][0])[2];
      ((float4*)kk)[3] = ((const float4*)&Kt[tid][0])[3];
      float ss = 0.f;
#pragma unroll
      for (int c = 0; c < 16; c++) ss += kk[c] * kk[c];
      float fc = 1.f / fmaxf(sqrtf(ss), 1e-12f);
#pragma unroll
      for (int c = 0; c < 16; c++) kk[c] *= fc;
      ((float4*)&Kt[tid][0])[0] = ((float4*)kk)[0];
      ((float4*)&Kt[tid][0])[1] = ((float4*)kk)[1];
      ((float4*)&Kt[tid][0])[2] = ((float4*)kk)[2];
      ((float4*)&Kt[tid][0])[3] = ((float4*)kk)[3];
    }
    __syncthreads();
#pragma unroll 2
    for (int mm = 0; mm < TM; mm++) {
      const float4* kr = (const float4*)(&Kt[mm][0]);
      const float4* vr = (const float4*)(&Vt[mm][0]);
      union { float4 v4[4]; f2 v2[8]; } ka, va;
      ka.v4[0] = kr[0]; ka.v4[1] = kr[1]; ka.v4[2] = kr[2]; ka.v4[3] = kr[3];
      va.v4[0] = vr[0]; va.v4[1] = vr[1]; va.v4[2] = vr[2]; va.v4[3] = vr[3];
      f2 sA = {0.f, 0.f}, sB = {0.f, 0.f};
#pragma unroll
      for (int i = 0; i < 4; i++) {
        sA = pk_fma(q2[i], ka.v2[i], sA);
        sB = pk_fma(q2[i + 4], ka.v2[i + 4], sB);
      }
      float sv = (sA.x + sA.y) + (sB.x + sB.y);
      float ea = __expf(fmaxf(sv * t2, 0.f));
      la += ea;
      f2 e2 = {ea, ea};
#pragma unroll
      for (int i = 0; i < 8; i++) o2[i] = pk_fma(e2, va.v2[i], o2[i]);
    }
  }

  size_t base = ((size_t)bh * SPLIT + s);
#pragma unroll
  for (int i = 0; i < 8; i++) {
    spl_o[(base * 16 + 2 * i) * NPIX + qi]     = o2[i].x;
    spl_o[(base * 16 + 2 * i + 1) * NPIX + qi] = o2[i].y;
  }
  spl_l[base * NPIX + qi] = la;
}

// ---------------- combine spatial partials: outs = (sum_s o) / (sum_s l) ----------------
// thread per (bh,n); grid 6*4096/64 = 384 blocks
__global__ __launch_bounds__(64) void sp_combine_kernel(
    const float* __restrict__ spl_o, const float* __restrict__ spl_l,
    float* __restrict__ outs)
{
  int gid = blockIdx.x * 64 + threadIdx.x;
  int n = gid & (NPIX - 1);
  int bh = gid >> 12;
  int b = bh / 3, h = bh % 3;
  float l = 0.f;
#pragma unroll
  for (int s = 0; s < SPLIT; s++) l += spl_l[((size_t)bh * SPLIT + s) * NPIX + n];
  float inv = 1.f / l;
#pragma unroll
  for (int c = 0; c < 16; c++) {
    float o = 0.f;
#pragma unroll
    for (int s = 0; s < SPLIT; s++)
      o += spl_o[(((size_t)bh * SPLIT + s) * 16 + c) * NPIX + n];
    outs[(size_t)(b * 48 + h * 16 + c) * NPIX + n] = o * inv;
  }
}

// ---------------- project outc/outs + residual -> y ----------------
// grid: B*(N/64)*4 (o-split 4) = 512 blocks, block 64
__global__ __launch_bounds__(64) void proj_kernel(
    const float* __restrict__ inp, const float* __restrict__ outc,
    const float* __restrict__ outs, const float* __restrict__ po1_w,
    const float* __restrict__ po1_b, const float* __restrict__ po2_w,
    const float* __restrict__ po2_b, const float* __restrict__ beta,
    const float* __restrict__ beta2, float* __restrict__ y_ws)
{
  int bid = blockIdx.x;
  int os = bid & 3; bid >>= 2;
  int b = bid >> 6;
  int n = ((bid & 63) << 6) + threadIdx.x;
  float oc[48], ov[48];
  const float* pc = outc + (size_t)b * 48 * NPIX;
  const float* ps = outs + (size_t)b * 48 * NPIX;
#pragma unroll
  for (int c = 0; c < 48; c++) { oc[c] = pc[c * NPIX + n]; ov[c] = ps[c * NPIX + n]; }
  for (int o = os * 12; o < os * 12 + 12; o++) {
    const float* w1 = po1_w + o * 48;
    const float* w2 = po2_w + o * 48;
    float a1 = 0.f, a2 = 0.f;
#pragma unroll
    for (int c = 0; c < 48; c++) { a1 += w1[c] * oc[c]; a2 += w2[c] * ov[c]; }
    float yv = inp[(size_t)(b * 48 + o) * NPIX + n]
             + (a1 + po1_b[o]) * beta[o] + (a2 + po2_b[o]) * beta2[o];
    y_ws[(size_t)(b * 48 + o) * NPIX + n] = yv;
  }
}

// ---------------- LN2 + GLU FFN + residual -> out ----------------
// grid: B*(N/32) = 256 blocks, 256 threads: 32 pixels x 8 j-groups (split-j
// over the 48 gate channels, LDS reduce; stride 49 = conflict-free)
__global__ __launch_bounds__(256) void ffn_kernel(
    const float* __restrict__ y_ws, const float* __restrict__ conv4_w,
    const float* __restrict__ conv4_b, const float* __restrict__ conv5_w,
    const float* __restrict__ conv5_b, const float* __restrict__ ln2_w,
    const float* __restrict__ ln2_b, const float* __restrict__ gamma,
    float* __restrict__ outp)
{
  int bid = blockIdx.x;
  int b = bid >> 7;
  int n0 = (bid & 127) << 5;
  int tid = threadIdx.x;
  int p = tid & 31, jg = tid >> 5;   // pixel-in-tile, j-group 0..7
  int n = n0 + p;
  const float* src = y_ws + (size_t)b * 48 * NPIX;

  // LN2 (recomputed per j-group; loads are cache hits)
  float t[48];
  float mu = 0.f;
#pragma unroll
  for (int c = 0; c < 48; c++) { t[c] = src[c * NPIX + n]; mu += t[c]; }
  mu *= (1.f / 48.f);
  float var = 0.f;
#pragma unroll
  for (int c = 0; c < 48; c++) { float d = t[c] - mu; var += d * d; }
  var *= (1.f / 48.f);
  float rstd = 1.f / sqrtf(var + 1e-6f);
#pragma unroll
  for (int c = 0; c < 48; c++) t[c] = (t[c] - mu) * rstd * ln2_w[c] + ln2_b[c];

  float fa[48];
#pragma unroll
  for (int o = 0; o < 48; o++) fa[o] = 0.f;
  for (int j = jg * 6; j < jg * 6 + 6; j++) {
    const float* w4a = conv4_w + j * 48;
    const float* w4b = conv4_w + (j + 48) * 48;
    float g1 = conv4_b[j], g2 = conv4_b[j + 48];
#pragma unroll
    for (int c = 0; c < 48; c++) { g1 += w4a[c] * t[c]; g2 += w4b[c] * t[c]; }
    float hh = g1 * g2;
#pragma unroll
    for (int o = 0; o < 48; o++) fa[o] += conv5_w[o * 48 + j] * hh;
  }

  __shared__ float part[8][32][49];   // ~49 KiB
#pragma unroll
  for (int o = 0; o < 48; o++) part[jg][p][o] = fa[o];
  __syncthreads();
  // group jg writes outputs o = jg*6 .. jg*6+5 at pixel p
#pragma unroll
  for (int oo = 0; oo < 6; oo++) {
    int o = jg * 6 + oo;
    float sum = 0.f;
#pragma unroll
    for (int g = 0; g < 8; g++) sum += part[g][p][o];
    outp[(size_t)(b * 48 + o) * NPIX + n] =
        src[o * NPIX + n] + (sum + conv5_b[o]) * gamma[o];
  }
}

extern "C" void kernel_launch(void* const* d_in, const int* in_sizes, int n_in,
                              void* d_out, int out_size, void* d_ws, size_t ws_size,
                              hipStream_t stream)
{
  (void)in_sizes; (void)n_in; (void)out_size; (void)ws_size;
  const float* inp     = (const float*)d_in[0];
  const float* qkv_w   = (const float*)d_in[1];
  const float* qkv_b   = (const float*)d_in[2];
  const float* dw_w    = (const float*)d_in[3];
  const float* dw_b    = (const float*)d_in[4];
  const float* po1_w   = (const float*)d_in[5];
  const float* po1_b   = (const float*)d_in[6];
  const float* po2_w   = (const float*)d_in[7];
  const float* po2_b   = (const float*)d_in[8];
  const float* temp1   = (const float*)d_in[9];
  const float* temp2   = (const float*)d_in[10];
  const float* conv4_w = (const float*)d_in[11];
  const float* conv4_b = (const float*)d_in[12];
  const float* conv5_w = (const float*)d_in[13];
  const float* conv5_b = (const float*)d_in[14];
  const float* ln1_w   = (const float*)d_in[15];
  const float* ln1_b   = (const float*)d_in[16];
  const float* ln2_w   = (const float*)d_in[17];
  const float* ln2_b   = (const float*)d_in[18];
  const float* beta    = (const float*)d_in[19];
  const float* beta2   = (const float*)d_in[20];
  const float* gamma   = (const float*)d_in[21];
  float* out = (float*)d_out;

  float* ws      = (float*)d_ws;
  float* t_buf   = ws;                 // dead after dwconv
  float* spl_l   = ws;                 // overlays t_buf
  float* cd_norm = ws + 196608;        // overlays t_buf
  float* cd_dot  = ws + 202752;        // overlays t_buf
  float* outs    = ws + 251904;        // overlays t_buf
  float* qkvb    = ws + 1179648;
  float* outc    = ws + 2359296;
  float* y_ws    = ws + 2752512;
  float* spl_o   = ws + 3145728;
  // total ws use: 6,291,456 floats (25.2 MB)

  // 1) LN1 + qkv 1x1 conv
  ln_qkv_kernel<<<2 * 64 * 8, 64, 0, stream>>>(inp, qkv_w, qkv_b, ln1_w, ln1_b, t_buf);
  // 2) depthwise 3x3
  dwconv_kernel<<<(2 * 144 * NPIX) / 256, 256, 0, stream>>>(t_buf, dw_w, dw_b, qkvb);
  // 3a) channel attention: partial norms + dots
  chattn_dots_kernel<<<192, 256, 0, stream>>>(qkvb, cd_norm, cd_dot);
  // 3b) channel attention: softmax + PV
  chattn_pv_kernel<<<96, 256, 0, stream>>>(qkvb, cd_norm, cd_dot, temp1, outc);
  // 4) spatial attention (flash, split-m, packed fp32)
  spattn_kernel<<<6 * SPLIT * 64, 64, 0, stream>>>(qkvb, temp2, spl_o, spl_l);
  // 5) combine spatial partials
  sp_combine_kernel<<<(6 * NPIX) / 64, 64, 0, stream>>>(spl_o, spl_l, outs);
  // 6) output projections + residual
  proj_kernel<<<2 * 64 * 4, 64, 0, stream>>>(inp, outc, outs, po1_w, po1_b,
                                             po2_w, po2_b, beta, beta2, y_ws);
  // 7) LN2 + GLU FFN + residual
  ffn_kernel<<<2 * 128, 256, 0, stream>>>(y_ws, conv4_w, conv4_b, conv5_w, conv5_b,
                                          ln2_w, ln2_b, gamma, out);
}

// Round 8
// 214.638 us; speedup vs baseline: 1.8990x; 1.4615x over previous
//
#include <hip/hip_runtime.h>
#include <math.h>

// Problem constants (B=2, C=48, HEADS=3, H=W=64)
#define NPIX 4096     // H*W
#define SPLIT 8       // spatial-attn m-splits

typedef unsigned short u16;
typedef short bf16x4 __attribute__((ext_vector_type(4)));   // 4 bf16 = 2 VGPR
typedef float f32x4 __attribute__((ext_vector_type(4)));    // 4 f32

// Workspace layout (float offsets); total 6,291,456 floats = 25.2 MB (proven size)
//  t_buf   @ 0        [B][144][N]    conv1x1(LN(inp)) pre-dwconv  (dead after dwconv)
//    spl_l   @ 0       [6][8][N]     spatial-attn partial l          (ends 196608)
//    cd_norm @ 196608  [6][32][32]   chattn partial row-norms        (ends 202752)
//    cd_dot  @ 202752  [6][32][16][16] chattn partial dots           (ends 251904)
//    Vb      @ 251904  [6][16][4096] bf16 V (live prep..spattn)      (ends 448512)
//    outs    @ 251904  [B][48][N]    combined outs (written AFTER spattn, over Vb)
//    Qb      @ 645120  [6][4096][16] bf16 normalized Q               (ends 841728)
//    Kb      @ 841728  [6][4096][16] bf16 normalized K               (ends 1038336)
//  qkvb    @ 1179648  [B][144][N]    post-dwconv q/k/v (fp32)
//  outc    @ 2359296  [B][48][N]     channel-attn output
//  y_ws    @ 2752512  [B][48][N]     post-attn residual y
//  spl_o   @ 3145728  [6][8][16][N]  spatial-attn partial O          (ends 6291456)

static __device__ __forceinline__ u16 bf16_rne(float f) {
  unsigned int u = __float_as_uint(f);
  return (u16)((u + 0x7FFFu + ((u >> 16) & 1u)) >> 16);
}

#if __has_builtin(__builtin_amdgcn_mfma_f32_16x16x16bf16_1k)
static __device__ __forceinline__ f32x4 mfma16(bf16x4 a, bf16x4 b, f32x4 c) {
  return __builtin_amdgcn_mfma_f32_16x16x16bf16_1k(a, b, c, 0, 0, 0);
}
#else
// fallback: raw instruction + conservative hazard padding (builtin normally used)
static __device__ __forceinline__ f32x4 mfma16(bf16x4 a, bf16x4 b, f32x4 c) {
  f32x4 d;
  asm volatile("s_nop 1\n\t"
               "v_mfma_f32_16x16x16_bf16 %0, %1, %2, %3\n\t"
               "s_nop 7\n\ts_nop 7"
               : "=v"(d) : "v"(a), "v"(b), "v"(c));
  return d;
}
#endif

// ---------------- LN1 + qkv conv1x1 ----------------
// grid: B*(N/64)*8 (o-split 8) = 1024 blocks, block 64.
__global__ __launch_bounds__(64) void ln_qkv_kernel(
    const float* __restrict__ inp, const float* __restrict__ qkv_w,
    const float* __restrict__ qkv_b, const float* __restrict__ ln1_w,
    const float* __restrict__ ln1_b, float* __restrict__ t_buf)
{
  int bid = blockIdx.x;
  int os = bid & 7; bid >>= 3;
  int b = bid >> 6;
  int n = ((bid & 63) << 6) + threadIdx.x;
  const float* src = inp + (size_t)b * 48 * NPIX;
  float x[48];
  float mu = 0.f;
#pragma unroll
  for (int c = 0; c < 48; c++) { x[c] = src[c * NPIX + n]; mu += x[c]; }
  mu *= (1.f / 48.f);
  float var = 0.f;
#pragma unroll
  for (int c = 0; c < 48; c++) { float d = x[c] - mu; var += d * d; }
  var *= (1.f / 48.f);
  float rstd = 1.f / sqrtf(var + 1e-6f);
#pragma unroll
  for (int c = 0; c < 48; c++) x[c] = (x[c] - mu) * rstd * ln1_w[c] + ln1_b[c];
  float* dst = t_buf + (size_t)b * 144 * NPIX + n;
  for (int o = os * 18; o < os * 18 + 18; o++) {
    const float* wr = qkv_w + o * 48;
    float a0 = 0.f, a1 = 0.f;
#pragma unroll
    for (int c = 0; c < 48; c += 2) { a0 += wr[c] * x[c]; a1 += wr[c + 1] * x[c + 1]; }
    dst[(size_t)o * NPIX] = a0 + a1 + qkv_b[o];
  }
}

// ---------------- depthwise 3x3 + bias ----------------
// thread per (b,ch,pixel); grid 2*144*4096/256 = 4608
__global__ __launch_bounds__(256) void dwconv_kernel(
    const float* __restrict__ t_buf, const float* __restrict__ dw_w,
    const float* __restrict__ dw_b, float* __restrict__ qkvb)
{
  int gid = blockIdx.x * 256 + threadIdx.x;
  int n = gid & (NPIX - 1);
  int bc = gid >> 12;           // 0..287
  int ch = bc % 144;
  int i = n >> 6, j = n & 63;
  const float* src = t_buf + (size_t)bc * NPIX;
  float acc = dw_b[ch];
#pragma unroll
  for (int di = 0; di < 3; di++) {
    int ii = i + di - 1;
    if (ii < 0 || ii > 63) continue;
#pragma unroll
    for (int dj = 0; dj < 3; dj++) {
      int jj = j + dj - 1;
      if (jj < 0 || jj > 63) continue;
      acc += src[ii * 64 + jj] * dw_w[ch * 9 + di * 3 + dj];
    }
  }
  qkvb[(size_t)bc * NPIX + n] = acc;
}

// ---------------- prep: l2-normalize q,k over cph + cvt q,k,v to bf16 ----------------
// grid 384 blocks x 256. bid<192: q/k rows [n][16ch]; else: v cvt [ch][n].
__global__ __launch_bounds__(256) void prep_bf16_kernel(
    const float* __restrict__ qkv, u16* __restrict__ Qb,
    u16* __restrict__ Kb, u16* __restrict__ Vb)
{
  int gid = blockIdx.x * 256 + threadIdx.x;
  if (gid < 49152) {
    int n = gid & 4095;
    int bhw = gid >> 12;         // 0..11
    int which = bhw / 6;         // 0=q, 1=k
    int bh = bhw % 6;
    int b = bh / 3, h = bh % 3;
    const float* src = qkv + (size_t)(b * 144 + which * 48 + h * 16) * NPIX + n;
    float v[16]; float ss = 0.f;
#pragma unroll
    for (int c = 0; c < 16; c++) { v[c] = src[(size_t)c * NPIX]; ss += v[c] * v[c]; }
    float fc = 1.f / fmaxf(sqrtf(ss), 1e-12f);
    unsigned int w[8];
#pragma unroll
    for (int i = 0; i < 8; i++) {
      unsigned int lo = bf16_rne(v[2 * i] * fc);
      unsigned int hi = bf16_rne(v[2 * i + 1] * fc);
      w[i] = lo | (hi << 16);
    }
    u16* dst = (which ? Kb : Qb) + ((size_t)bh * 4096 + n) * 16;
    ((uint4*)dst)[0] = make_uint4(w[0], w[1], w[2], w[3]);
    ((uint4*)dst)[1] = make_uint4(w[4], w[5], w[6], w[7]);
  } else {
    int e = (gid - 49152) * 8;   // v element index, 6*16*4096 total
    int bh = e >> 16;
    int ch = (e >> 12) & 15;
    int n0 = e & 4095;
    int b = bh / 3, h = bh % 3;
    const float* src = qkv + (size_t)(b * 144 + 96 + h * 16 + ch) * NPIX + n0;
    float4 a = *(const float4*)(src);
    float4 bb = *(const float4*)(src + 4);
    unsigned int w0 = bf16_rne(a.x) | ((unsigned)bf16_rne(a.y) << 16);
    unsigned int w1 = bf16_rne(a.z) | ((unsigned)bf16_rne(a.w) << 16);
    unsigned int w2 = bf16_rne(bb.x) | ((unsigned)bf16_rne(bb.y) << 16);
    unsigned int w3 = bf16_rne(bb.z) | ((unsigned)bf16_rne(bb.w) << 16);
    u16* dst = Vb + (size_t)bh * 65536 + (size_t)ch * 4096 + n0;
    *((uint4*)dst) = make_uint4(w0, w1, w2, w3);
  }
}

// ---------------- channel attention, stage A: partial norms + dots ----------------
__global__ __launch_bounds__(256) void chattn_dots_kernel(
    const float* __restrict__ qkv, float* __restrict__ cd_norm,
    float* __restrict__ cd_dot)
{
  int bid = blockIdx.x;
  int nc = bid & 31, bh = bid >> 5;
  int b = bh / 3, h = bh % 3;
  int tid = threadIdx.x;
  const float* q = qkv + (size_t)(b * 144 + h * 16) * NPIX;
  const float* k = qkv + (size_t)(b * 144 + 48 + h * 16) * NPIX;

  __shared__ float part[32][9];

  {
    int r = tid >> 3, pp = tid & 7;
    const float* s2 = ((r < 16) ? (q + r * NPIX) : (k + (r - 16) * NPIX))
                    + nc * 128 + pp * 16;
    float ss = 0.f;
#pragma unroll
    for (int i = 0; i < 16; i += 4) {
      float4 xx = *(const float4*)(s2 + i);
      ss += xx.x * xx.x + xx.y * xx.y + xx.z * xx.z + xx.w * xx.w;
    }
    part[r][pp] = ss;
  }
  int c = tid >> 4, d = tid & 15;
  const float* qc = q + c * NPIX + nc * 128;
  const float* kd = k + d * NPIX + nc * 128;
  float acc = 0.f;
  for (int i = 0; i < 128; i += 4) {
    float4 xq = *(const float4*)(qc + i);
    float4 xk = *(const float4*)(kd + i);
    acc += xq.x * xk.x + xq.y * xk.y + xq.z * xk.z + xq.w * xk.w;
  }
  __syncthreads();
  if (tid < 32) {
    float ss = 0.f;
#pragma unroll
    for (int pp = 0; pp < 8; pp++) ss += part[tid][pp];
    cd_norm[(size_t)(bh * 32 + nc) * 32 + tid] = ss;
  }
  cd_dot[((size_t)(bh * 32 + nc) * 16 + c) * 16 + d] = acc;
}

// ---------------- channel attention, stage B: softmax + PV ----------------
__global__ __launch_bounds__(256) void chattn_pv_kernel(
    const float* __restrict__ qkv, const float* __restrict__ cd_norm,
    const float* __restrict__ cd_dot, const float* __restrict__ temp1,
    float* __restrict__ outc)
{
  int bid = blockIdx.x;
  int ns = bid & 15, bh = bid >> 4;
  int b = bh / 3, h = bh % 3;
  int tid = threadIdx.x;
  const float* v = qkv + (size_t)(b * 144 + 96 + h * 16) * NPIX;

  __shared__ float fac[32];
  __shared__ float atte[16][17];
  __shared__ float att[16][17];

  if (tid < 32) {
    float ss = 0.f;
#pragma unroll
    for (int nc = 0; nc < 32; nc++) ss += cd_norm[(size_t)(bh * 32 + nc) * 32 + tid];
    fac[tid] = 1.f / fmaxf(sqrtf(ss), 1e-12f);
  }
  __syncthreads();
  int cc = tid >> 4, dd = tid & 15;
  float t1 = temp1[h];
  if (tid < 256) {
    float a = 0.f;
#pragma unroll
    for (int nc = 0; nc < 32; nc++)
      a += cd_dot[((size_t)(bh * 32 + nc) * 16 + cc) * 16 + dd];
    float z = fmaxf(a * fac[cc] * fac[16 + dd] * t1, 0.f);
    atte[cc][dd] = __expf(z);
  }
  __syncthreads();
  if (tid < 256) {
    float rs = 0.f;
#pragma unroll
    for (int d2 = 0; d2 < 16; d2++) rs += atte[cc][d2];
    att[cc][dd] = atte[cc][dd] / rs;
  }
  __syncthreads();

  int n2 = ns * 256 + tid;
  float vv[16];
#pragma unroll
  for (int d2 = 0; d2 < 16; d2++) vv[d2] = v[d2 * NPIX + n2];
#pragma unroll
  for (int c2 = 0; c2 < 16; c2++) {
    float a = 0.f;
#pragma unroll
    for (int d2 = 0; d2 < 16; d2++) a += att[c2][d2] * vv[d2];
    outc[(size_t)(b * 48 + h * 16 + c2) * NPIX + n2] = a;
  }
}

// ---------------- spatial attention: bf16 MFMA flash (no-max, z in [0,|t2|]) ----------------
// grid: 6 bh * 8 s * 64 qt = 3072 blocks, 64 threads (1 wave), no LDS, no barriers.
// Per wave: 64 queries (4 sub-tiles of 16), m-range 512 (32 m-tiles of 16).
// S^T-tile = mfma(A=K-tile, B=Q-tile): D lane layout (col=lane&15=q, row=4g+r=m)
// equals PV's B-operand layout (k=4g+j=m, col=lane&15=q) -> P converts in-lane.
// outs^T accumulates in C across all m-tiles; l(q) in-lane + 2 shfl_xor at end.
__global__ __launch_bounds__(64) void spattn_kernel(
    const u16* __restrict__ Qb, const u16* __restrict__ Kb,
    const u16* __restrict__ Vb, const float* __restrict__ temp2,
    float* __restrict__ spl_o, float* __restrict__ spl_l)
{
  int bid = blockIdx.x;
  int qt = bid & 63;
  int s = (bid >> 6) & 7;
  int bh = bid >> 9;             // 0..5
  int l = threadIdx.x;
  int ql = l & 15, g = l >> 4;
  float t2 = temp2[bh % 3];

  const u16* Qp = Qb + (size_t)bh * 4096 * 16;
  const u16* Kp = Kb + (size_t)bh * 4096 * 16;
  const u16* Vp = Vb + (size_t)bh * 65536;

  // Q B-fragments (persist across the whole m-loop)
  bf16x4 qf[4];
#pragma unroll
  for (int sub = 0; sub < 4; sub++) {
    int q = qt * 64 + sub * 16 + ql;
    qf[sub] = *(const bf16x4*)(Qp + (size_t)q * 16 + 4 * g);
  }
  f32x4 oacc[4];
  float la[4];
#pragma unroll
  for (int sub = 0; sub < 4; sub++) {
    oacc[sub] = (f32x4){0.f, 0.f, 0.f, 0.f};
    la[sub] = 0.f;
  }

  int m0 = s * 512;
  const u16* kptr = Kp + (size_t)(m0 + ql) * 16 + 4 * g;   // A1: row=m(ql), k=ch(4g+j)
  const u16* vptr = Vp + (size_t)ql * 4096 + m0 + 4 * g;   // A2: row=ch(ql), k=m(4g+j)
  const f32x4 zero4 = (f32x4){0.f, 0.f, 0.f, 0.f};

#pragma unroll 2
  for (int t = 0; t < 32; t++) {
    bf16x4 kf = *(const bf16x4*)kptr;  kptr += 256;  // next 16 m-rows x 16 ch
    bf16x4 vf = *(const bf16x4*)vptr;  vptr += 16;   // next 16 m along n
#pragma unroll
    for (int sub = 0; sub < 4; sub++) {
      f32x4 sv = mfma16(kf, qf[sub], zero4);         // S^T tile
      float p0 = __expf(fmaxf(sv.x * t2, 0.f));
      float p1 = __expf(fmaxf(sv.y * t2, 0.f));
      float p2 = __expf(fmaxf(sv.z * t2, 0.f));
      float p3 = __expf(fmaxf(sv.w * t2, 0.f));
      la[sub] += (p0 + p1) + (p2 + p3);
      // truncate-pack P to bf16 (softmax ratio cancels the tiny bias)
      unsigned int lo = (__float_as_uint(p0) >> 16) | (__float_as_uint(p1) & 0xFFFF0000u);
      unsigned int hi = (__float_as_uint(p2) >> 16) | (__float_as_uint(p3) & 0xFFFF0000u);
      uint2 pu = make_uint2(lo, hi);
      bf16x4 pf = *(bf16x4*)&pu;
      oacc[sub] = mfma16(vf, pf, oacc[sub]);         // outs^T += V * P
    }
  }

  size_t base = (size_t)bh * SPLIT + s;
#pragma unroll
  for (int sub = 0; sub < 4; sub++) {
    float lv = la[sub];
    lv += __shfl_xor(lv, 16);
    lv += __shfl_xor(lv, 32);
    int q = qt * 64 + sub * 16 + ql;
    spl_o[(base * 16 + 4 * g + 0) * NPIX + q] = oacc[sub].x;
    spl_o[(base * 16 + 4 * g + 1) * NPIX + q] = oacc[sub].y;
    spl_o[(base * 16 + 4 * g + 2) * NPIX + q] = oacc[sub].z;
    spl_o[(base * 16 + 4 * g + 3) * NPIX + q] = oacc[sub].w;
    if (g == 0) spl_l[base * NPIX + q] = lv;
  }
}

// ---------------- combine spatial partials: outs = (sum_s o) / (sum_s l) ----------------
__global__ __launch_bounds__(64) void sp_combine_kernel(
    const float* __restrict__ spl_o, const float* __restrict__ spl_l,
    float* __restrict__ outs)
{
  int gid = blockIdx.x * 64 + threadIdx.x;
  int n = gid & (NPIX - 1);
  int bh = gid >> 12;
  int b = bh / 3, h = bh % 3;
  float l = 0.f;
#pragma unroll
  for (int s = 0; s < SPLIT; s++) l += spl_l[((size_t)bh * SPLIT + s) * NPIX + n];
  float inv = 1.f / l;
#pragma unroll
  for (int c = 0; c < 16; c++) {
    float o = 0.f;
#pragma unroll
    for (int s = 0; s < SPLIT; s++)
      o += spl_o[(((size_t)bh * SPLIT + s) * 16 + c) * NPIX + n];
    outs[(size_t)(b * 48 + h * 16 + c) * NPIX + n] = o * inv;
  }
}

// ---------------- project outc/outs + residual -> y ----------------
__global__ __launch_bounds__(64) void proj_kernel(
    const float* __restrict__ inp, const float* __restrict__ outc,
    const float* __restrict__ outs, const float* __restrict__ po1_w,
    const float* __restrict__ po1_b, const float* __restrict__ po2_w,
    const float* __restrict__ po2_b, const float* __restrict__ beta,
    const float* __restrict__ beta2, float* __restrict__ y_ws)
{
  int bid = blockIdx.x;
  int os = bid & 3; bid >>= 2;
  int b = bid >> 6;
  int n = ((bid & 63) << 6) + threadIdx.x;
  float oc[48], ov[48];
  const float* pc = outc + (size_t)b * 48 * NPIX;
  const float* ps = outs + (size_t)b * 48 * NPIX;
#pragma unroll
  for (int c = 0; c < 48; c++) { oc[c] = pc[c * NPIX + n]; ov[c] = ps[c * NPIX + n]; }
  for (int o = os * 12; o < os * 12 + 12; o++) {
    const float* w1 = po1_w + o * 48;
    const float* w2 = po2_w + o * 48;
    float a1 = 0.f, a2 = 0.f;
#pragma unroll
    for (int c = 0; c < 48; c++) { a1 += w1[c] * oc[c]; a2 += w2[c] * ov[c]; }
    float yv = inp[(size_t)(b * 48 + o) * NPIX + n]
             + (a1 + po1_b[o]) * beta[o] + (a2 + po2_b[o]) * beta2[o];
    y_ws[(size_t)(b * 48 + o) * NPIX + n] = yv;
  }
}

// ---------------- LN2 + GLU FFN + residual -> out ----------------
__global__ __launch_bounds__(256) void ffn_kernel(
    const float* __restrict__ y_ws, const float* __restrict__ conv4_w,
    const float* __restrict__ conv4_b, const float* __restrict__ conv5_w,
    const float* __restrict__ conv5_b, const float* __restrict__ ln2_w,
    const float* __restrict__ ln2_b, const float* __restrict__ gamma,
    float* __restrict__ outp)
{
  int bid = blockIdx.x;
  int b = bid >> 7;
  int n0 = (bid & 127) << 5;
  int tid = threadIdx.x;
  int p = tid & 31, jg = tid >> 5;   // pixel-in-tile, j-group 0..7
  int n = n0 + p;
  const float* src = y_ws + (size_t)b * 48 * NPIX;

  float t[48];
  float mu = 0.f;
#pragma unroll
  for (int c = 0; c < 48; c++) { t[c] = src[c * NPIX + n]; mu += t[c]; }
  mu *= (1.f / 48.f);
  float var = 0.f;
#pragma unroll
  for (int c = 0; c < 48; c++) { float d = t[c] - mu; var += d * d; }
  var *= (1.f / 48.f);
  float rstd = 1.f / sqrtf(var + 1e-6f);
#pragma unroll
  for (int c = 0; c < 48; c++) t[c] = (t[c] - mu) * rstd * ln2_w[c] + ln2_b[c];

  float fa[48];
#pragma unroll
  for (int o = 0; o < 48; o++) fa[o] = 0.f;
  for (int j = jg * 6; j < jg * 6 + 6; j++) {
    const float* w4a = conv4_w + j * 48;
    const float* w4b = conv4_w + (j + 48) * 48;
    float g1 = conv4_b[j], g2 = conv4_b[j + 48];
#pragma unroll
    for (int c = 0; c < 48; c++) { g1 += w4a[c] * t[c]; g2 += w4b[c] * t[c]; }
    float hh = g1 * g2;
#pragma unroll
    for (int o = 0; o < 48; o++) fa[o] += conv5_w[o * 48 + j] * hh;
  }

  __shared__ float part[8][32][49];   // ~49 KiB, stride 49 = conflict-free
#pragma unroll
  for (int o = 0; o < 48; o++) part[jg][p][o] = fa[o];
  __syncthreads();
#pragma unroll
  for (int oo = 0; oo < 6; oo++) {
    int o = jg * 6 + oo;
    float sum = 0.f;
#pragma unroll
    for (int g = 0; g < 8; g++) sum += part[g][p][o];
    outp[(size_t)(b * 48 + o) * NPIX + n] =
        src[o * NPIX + n] + (sum + conv5_b[o]) * gamma[o];
  }
}

extern "C" void kernel_launch(void* const* d_in, const int* in_sizes, int n_in,
                              void* d_out, int out_size, void* d_ws, size_t ws_size,
                              hipStream_t stream)
{
  (void)in_sizes; (void)n_in; (void)out_size; (void)ws_size;
  const float* inp     = (const float*)d_in[0];
  const float* qkv_w   = (const float*)d_in[1];
  const float* qkv_b   = (const float*)d_in[2];
  const float* dw_w    = (const float*)d_in[3];
  const float* dw_b    = (const float*)d_in[4];
  const float* po1_w   = (const float*)d_in[5];
  const float* po1_b   = (const float*)d_in[6];
  const float* po2_w   = (const float*)d_in[7];
  const float* po2_b   = (const float*)d_in[8];
  const float* temp1   = (const float*)d_in[9];
  const float* temp2   = (const float*)d_in[10];
  const float* conv4_w = (const float*)d_in[11];
  const float* conv4_b = (const float*)d_in[12];
  const float* conv5_w = (const float*)d_in[13];
  const float* conv5_b = (const float*)d_in[14];
  const float* ln1_w   = (const float*)d_in[15];
  const float* ln1_b   = (const float*)d_in[16];
  const float* ln2_w   = (const float*)d_in[17];
  const float* ln2_b   = (const float*)d_in[18];
  const float* beta    = (const float*)d_in[19];
  const float* beta2   = (const float*)d_in[20];
  const float* gamma   = (const float*)d_in[21];
  float* out = (float*)d_out;

  float* ws      = (float*)d_ws;
  float* t_buf   = ws;                 // dead after dwconv
  float* spl_l   = ws;                 // overlays t_buf
  float* cd_norm = ws + 196608;
  float* cd_dot  = ws + 202752;
  u16*   Vb      = (u16*)(ws + 251904);   // live prep..spattn
  float* outs    = ws + 251904;           // written after spattn (over Vb)
  u16*   Qb      = (u16*)(ws + 645120);
  u16*   Kb      = (u16*)(ws + 841728);
  float* qkvb    = ws + 1179648;
  float* outc    = ws + 2359296;
  float* y_ws    = ws + 2752512;
  float* spl_o   = ws + 3145728;
  // total ws use: 6,291,456 floats (25.2 MB)

  // 1) LN1 + qkv 1x1 conv
  ln_qkv_kernel<<<2 * 64 * 8, 64, 0, stream>>>(inp, qkv_w, qkv_b, ln1_w, ln1_b, t_buf);
  // 2) depthwise 3x3
  dwconv_kernel<<<(2 * 144 * NPIX) / 256, 256, 0, stream>>>(t_buf, dw_w, dw_b, qkvb);
  // 3) prep: normalize q,k + bf16 conversion of q,k,v
  prep_bf16_kernel<<<384, 256, 0, stream>>>(qkvb, Qb, Kb, Vb);
  // 4a) channel attention: partial norms + dots
  chattn_dots_kernel<<<192, 256, 0, stream>>>(qkvb, cd_norm, cd_dot);
  // 4b) channel attention: softmax + PV
  chattn_pv_kernel<<<96, 256, 0, stream>>>(qkvb, cd_norm, cd_dot, temp1, outc);
  // 5) spatial attention (bf16 MFMA flash, split-m)
  spattn_kernel<<<6 * SPLIT * 64, 64, 0, stream>>>(Qb, Kb, Vb, temp2, spl_o, spl_l);
  // 6) combine spatial partials
  sp_combine_kernel<<<(6 * NPIX) / 64, 64, 0, stream>>>(spl_o, spl_l, outs);
  // 7) output projections + residual
  proj_kernel<<<2 * 64 * 4, 64, 0, stream>>>(inp, outc, outs, po1_w, po1_b,
                                             po2_w, po2_b, beta, beta2, y_ws);
  // 8) LN2 + GLU FFN + residual
  ffn_kernel<<<2 * 128, 256, 0, stream>>>(y_ws, conv4_w, conv4_b, conv5_w, conv5_b,
                                          ln2_w, ln2_b, gamma, out);
}

// Round 12
// 211.193 us; speedup vs baseline: 1.9299x; 1.0163x over previous
//
#include <hip/hip_runtime.h>
#include <math.h>

// Problem constants (B=2, C=48, HEADS=3, H=W=64)
#define NPIX 4096     // H*W
#define SPLIT 8       // spatial-attn m-splits

typedef unsigned short u16;
typedef short bf16x4 __attribute__((ext_vector_type(4)));   // 4 bf16 = 2 VGPR
typedef float f32x4 __attribute__((ext_vector_type(4)));    // 4 f32

// Workspace layout (float offsets); total 6,291,456 floats = 25.2 MB (proven size)
//  t_buf   @ 0        [B][144][N]     conv1x1(LN(inp)) pre-dwconv  (dead after dwconv)
//    spl_l   @ 0       [6][8][N]      spatial-attn partial l          (ends 196608)
//    cd_norm @ 196608  [6][64][32]    chattn partial row-norms        (ends 208896)
//    cd_dot  @ 208896  [6][64][16][16] chattn partial dots            (ends 307200)
//    Vb      @ 307200  [6][16][4096]u16 bf16 V (live prep..spattn)    (ends 503808)
//    outs    @ 307200  [B][48][N]     combined outs (AFTER spattn)    (ends 700416)
//    Qb      @ 700416  [6][4096][16]u16 bf16 normalized Q             (ends 897024)
//    Kb      @ 897024  [6][4096][16]u16 bf16 normalized K             (ends 1093632)
//  qkvb    @ 1179648  [B][144][N]     post-dwconv q/k/v (fp32)
//  outc    @ 2359296  [B][48][N]      channel-attn output
//  y_ws    @ 2752512  [B][48][N]      post-attn residual y
//  spl_o   @ 3145728  [6][8][16][N]   spatial-attn partial O          (ends 6291456)

static __device__ __forceinline__ u16 bf16_rne(float f) {
  unsigned int u = __float_as_uint(f);
  return (u16)((u + 0x7FFFu + ((u >> 16) & 1u)) >> 16);
}

#if __has_builtin(__builtin_amdgcn_mfma_f32_16x16x16bf16_1k)
static __device__ __forceinline__ f32x4 mfma16(bf16x4 a, bf16x4 b, f32x4 c) {
  return __builtin_amdgcn_mfma_f32_16x16x16bf16_1k(a, b, c, 0, 0, 0);
}
#else
static __device__ __forceinline__ f32x4 mfma16(bf16x4 a, bf16x4 b, f32x4 c) {
  f32x4 d;
  asm volatile("s_nop 1\n\t"
               "v_mfma_f32_16x16x16_bf16 %0, %1, %2, %3\n\t"
               "s_nop 7\n\ts_nop 7"
               : "=v"(d) : "v"(a), "v"(b), "v"(c));
  return d;
}
#endif

// ---------------- LN1 + qkv conv1x1 ----------------
// grid: B*(N/64)*16 (o-split 16) = 2048 blocks, block 64 (8 waves/CU).
__global__ __launch_bounds__(64) void ln_qkv_kernel(
    const float* __restrict__ inp, const float* __restrict__ qkv_w,
    const float* __restrict__ qkv_b, const float* __restrict__ ln1_w,
    const float* __restrict__ ln1_b, float* __restrict__ t_buf)
{
  int bid = blockIdx.x;
  int os = bid & 15; bid >>= 4;
  int b = bid >> 6;
  int n = ((bid & 63) << 6) + threadIdx.x;
  const float* src = inp + (size_t)b * 48 * NPIX;
  float x[48];
  float mu = 0.f;
#pragma unroll
  for (int c = 0; c < 48; c++) { x[c] = src[c * NPIX + n]; mu += x[c]; }
  mu *= (1.f / 48.f);
  float var = 0.f;
#pragma unroll
  for (int c = 0; c < 48; c++) { float d = x[c] - mu; var += d * d; }
  var *= (1.f / 48.f);
  float rstd = 1.f / sqrtf(var + 1e-6f);
#pragma unroll
  for (int c = 0; c < 48; c++) x[c] = (x[c] - mu) * rstd * ln1_w[c] + ln1_b[c];
  float* dst = t_buf + (size_t)b * 144 * NPIX + n;
  for (int o = os * 9; o < os * 9 + 9; o++) {
    const float* wr = qkv_w + o * 48;
    float a0 = 0.f, a1 = 0.f;
#pragma unroll
    for (int c = 0; c < 48; c += 2) { a0 += wr[c] * x[c]; a1 += wr[c + 1] * x[c + 1]; }
    dst[(size_t)o * NPIX] = a0 + a1 + qkv_b[o];
  }
}

// ---------------- depthwise 3x3 + bias ----------------
// thread per (b,ch,pixel); grid 2*144*4096/256 = 4608
__global__ __launch_bounds__(256) void dwconv_kernel(
    const float* __restrict__ t_buf, const float* __restrict__ dw_w,
    const float* __restrict__ dw_b, float* __restrict__ qkvb)
{
  int gid = blockIdx.x * 256 + threadIdx.x;
  int n = gid & (NPIX - 1);
  int bc = gid >> 12;           // 0..287
  int ch = bc % 144;
  int i = n >> 6, j = n & 63;
  const float* src = t_buf + (size_t)bc * NPIX;
  float acc = dw_b[ch];
#pragma unroll
  for (int di = 0; di < 3; di++) {
    int ii = i + di - 1;
    if (ii < 0 || ii > 63) continue;
#pragma unroll
    for (int dj = 0; dj < 3; dj++) {
      int jj = j + dj - 1;
      if (jj < 0 || jj > 63) continue;
      acc += src[ii * 64 + jj] * dw_w[ch * 9 + di * 3 + dj];
    }
  }
  qkvb[(size_t)bc * NPIX + n] = acc;
}

// ---------------- prep: l2-normalize q,k over cph + cvt q,k,v to bf16 ----------------
// grid 384 blocks x 256. gid<49152: q/k rows [n][16ch]; else: v cvt [ch][n].
__global__ __launch_bounds__(256) void prep_bf16_kernel(
    const float* __restrict__ qkv, u16* __restrict__ Qb,
    u16* __restrict__ Kb, u16* __restrict__ Vb)
{
  int gid = blockIdx.x * 256 + threadIdx.x;
  if (gid < 49152) {
    int n = gid & 4095;
    int bhw = gid >> 12;         // 0..11
    int which = bhw / 6;         // 0=q, 1=k
    int bh = bhw % 6;
    int b = bh / 3, h = bh % 3;
    const float* src = qkv + (size_t)(b * 144 + which * 48 + h * 16) * NPIX + n;
    float v[16]; float ss = 0.f;
#pragma unroll
    for (int c = 0; c < 16; c++) { v[c] = src[(size_t)c * NPIX]; ss += v[c] * v[c]; }
    float fc = 1.f / fmaxf(sqrtf(ss), 1e-12f);
    unsigned int w[8];
#pragma unroll
    for (int i = 0; i < 8; i++) {
      unsigned int lo = bf16_rne(v[2 * i] * fc);
      unsigned int hi = bf16_rne(v[2 * i + 1] * fc);
      w[i] = lo | (hi << 16);
    }
    u16* dst = (which ? Kb : Qb) + ((size_t)bh * 4096 + n) * 16;
    ((uint4*)dst)[0] = make_uint4(w[0], w[1], w[2], w[3]);
    ((uint4*)dst)[1] = make_uint4(w[4], w[5], w[6], w[7]);
  } else {
    int e = (gid - 49152) * 8;   // v element index, 6*16*4096 total
    int bh = e >> 16;
    int ch = (e >> 12) & 15;
    int n0 = e & 4095;
    int b = bh / 3, h = bh % 3;
    const float* src = qkv + (size_t)(b * 144 + 96 + h * 16 + ch) * NPIX + n0;
    float4 a = *(const float4*)(src);
    float4 bb = *(const float4*)(src + 4);
    unsigned int w0 = bf16_rne(a.x) | ((unsigned)bf16_rne(a.y) << 16);
    unsigned int w1 = bf16_rne(a.z) | ((unsigned)bf16_rne(a.w) << 16);
    unsigned int w2 = bf16_rne(bb.x) | ((unsigned)bf16_rne(bb.y) << 16);
    unsigned int w3 = bf16_rne(bb.z) | ((unsigned)bf16_rne(bb.w) << 16);
    u16* dst = Vb + (size_t)bh * 65536 + (size_t)ch * 4096 + n0;
    *((uint4*)dst) = make_uint4(w0, w1, w2, w3);
  }
}

// ---------------- channel attention, stage A: partial norms + dots ----------------
// grid: 6 bh * 64 n-chunks = 384 blocks, 256 threads; chunk = 64 pixels.
__global__ __launch_bounds__(256) void chattn_dots_kernel(
    const float* __restrict__ qkv, float* __restrict__ cd_norm,
    float* __restrict__ cd_dot)
{
  int bid = blockIdx.x;
  int nc = bid & 63, bh = bid >> 6;
  int b = bh / 3, h = bh % 3;
  int tid = threadIdx.x;
  const float* q = qkv + (size_t)(b * 144 + h * 16) * NPIX;
  const float* k = qkv + (size_t)(b * 144 + 48 + h * 16) * NPIX;

  __shared__ float part[32][9];

  // row-norm partials: r = 0..31 (q rows 0-15, k rows 16-31), 8 partials of 8
  {
    int r = tid >> 3, pp = tid & 7;
    const float* s2 = ((r < 16) ? (q + r * NPIX) : (k + (r - 16) * NPIX))
                    + nc * 64 + pp * 8;
    float4 x0 = *(const float4*)(s2);
    float4 x1 = *(const float4*)(s2 + 4);
    part[r][pp] = x0.x * x0.x + x0.y * x0.y + x0.z * x0.z + x0.w * x0.w
                + x1.x * x1.x + x1.y * x1.y + x1.z * x1.z + x1.w * x1.w;
  }
  // dot: thread (c,d) over this 64-pixel chunk
  int c = tid >> 4, d = tid & 15;
  const float* qc = q + c * NPIX + nc * 64;
  const float* kd = k + d * NPIX + nc * 64;
  float acc = 0.f;
  for (int i = 0; i < 64; i += 4) {
    float4 xq = *(const float4*)(qc + i);
    float4 xk = *(const float4*)(kd + i);
    acc += xq.x * xk.x + xq.y * xk.y + xq.z * xk.z + xq.w * xk.w;
  }
  __syncthreads();
  if (tid < 32) {
    float ss = 0.f;
#pragma unroll
    for (int pp = 0; pp < 8; pp++) ss += part[tid][pp];
    cd_norm[(size_t)(bh * 64 + nc) * 32 + tid] = ss;
  }
  cd_dot[((size_t)(bh * 64 + nc) * 16 + c) * 16 + d] = acc;
}

// ---------------- channel attention, stage B: softmax + PV ----------------
// grid: 6 bh * 64 n-slices = 384 blocks, 128 threads (slice = 64 px, PV split
// 2-way over channels; att recomputed per block from partials — cheap).
__global__ __launch_bounds__(128) void chattn_pv_kernel(
    const float* __restrict__ qkv, const float* __restrict__ cd_norm,
    const float* __restrict__ cd_dot, const float* __restrict__ temp1,
    float* __restrict__ outc)
{
  int bid = blockIdx.x;
  int ns = bid & 63, bh = bid >> 6;
  int b = bh / 3, h = bh % 3;
  int tid = threadIdx.x;
  const float* v = qkv + (size_t)(b * 144 + 96 + h * 16) * NPIX;

  __shared__ float fac[32];
  __shared__ float atte[16][17];
  __shared__ float att[16][17];

  if (tid < 32) {
    float ss = 0.f;
    for (int nc = 0; nc < 64; nc++) ss += cd_norm[(size_t)(bh * 64 + nc) * 32 + tid];
    fac[tid] = 1.f / fmaxf(sqrtf(ss), 1e-12f);
  }
  __syncthreads();
  float t1 = temp1[h];
#pragma unroll
  for (int rep = 0; rep < 2; rep++) {
    int pair = tid + rep * 128;
    int cc = pair >> 4, dd = pair & 15;
    float a = 0.f;
    for (int nc = 0; nc < 64; nc++)
      a += cd_dot[((size_t)(bh * 64 + nc) * 16 + cc) * 16 + dd];
    float z = fmaxf(a * fac[cc] * fac[16 + dd] * t1, 0.f);
    atte[cc][dd] = __expf(z);
  }
  __syncthreads();
#pragma unroll
  for (int rep = 0; rep < 2; rep++) {
    int pair = tid + rep * 128;
    int cc = pair >> 4, dd = pair & 15;
    float rs = 0.f;
#pragma unroll
    for (int d2 = 0; d2 < 16; d2++) rs += atte[cc][d2];
    att[cc][dd] = atte[cc][dd] / rs;
  }
  __syncthreads();

  // PV: pixel = tid&63, channel half = tid>>6
  int n2 = ns * 64 + (tid & 63);
  int cg = tid >> 6;             // 0 or 1 -> channels cg*8..+8
  float vv[16];
#pragma unroll
  for (int d2 = 0; d2 < 16; d2++) vv[d2] = v[d2 * NPIX + n2];
#pragma unroll
  for (int c0 = 0; c0 < 8; c0++) {
    int c2 = cg * 8 + c0;
    float a = 0.f;
#pragma unroll
    for (int d2 = 0; d2 < 16; d2++) a += att[c2][d2] * vv[d2];
    outc[(size_t)(b * 48 + h * 16 + c2) * NPIX + n2] = a;
  }
}

// ---------------- spatial attention: bf16 MFMA flash (no-max, z in [0,|t2|]) ----------------
// grid: 6 bh * 8 s * 64 qt = 3072 blocks, 64 threads (1 wave), no LDS, no barriers.
// S^T-tile = mfma(A=K-tile, B=Q-tile); P converts in-lane; outs^T accumulates in C.
__global__ __launch_bounds__(64) void spattn_kernel(
    const u16* __restrict__ Qb, const u16* __restrict__ Kb,
    const u16* __restrict__ Vb, const float* __restrict__ temp2,
    float* __restrict__ spl_o, float* __restrict__ spl_l)
{
  int bid = blockIdx.x;
  int qt = bid & 63;
  int s = (bid >> 6) & 7;
  int bh = bid >> 9;             // 0..5
  int l = threadIdx.x;
  int ql = l & 15, g = l >> 4;
  float t2l = temp2[bh % 3] * 1.4426950408889634f;   // fold log2(e) -> exp2

  const u16* Qp = Qb + (size_t)bh * 4096 * 16;
  const u16* Kp = Kb + (size_t)bh * 4096 * 16;
  const u16* Vp = Vb + (size_t)bh * 65536;

  bf16x4 qf[4];
#pragma unroll
  for (int sub = 0; sub < 4; sub++) {
    int q = qt * 64 + sub * 16 + ql;
    qf[sub] = *(const bf16x4*)(Qp + (size_t)q * 16 + 4 * g);
  }
  f32x4 oacc[4];
  float la[4];
#pragma unroll
  for (int sub = 0; sub < 4; sub++) {
    oacc[sub] = (f32x4){0.f, 0.f, 0.f, 0.f};
    la[sub] = 0.f;
  }

  int m0 = s * 512;
  const u16* kptr = Kp + (size_t)(m0 + ql) * 16 + 4 * g;   // A1: row=m(ql), k=ch(4g+j)
  const u16* vptr = Vp + (size_t)ql * 4096 + m0 + 4 * g;   // A2: row=ch(ql), k=m(4g+j)
  const f32x4 zero4 = (f32x4){0.f, 0.f, 0.f, 0.f};

#pragma unroll 2
  for (int t = 0; t < 32; t++) {
    bf16x4 kf = *(const bf16x4*)kptr;  kptr += 256;
    bf16x4 vf = *(const bf16x4*)vptr;  vptr += 16;
#pragma unroll
    for (int sub = 0; sub < 4; sub++) {
      f32x4 sv = mfma16(kf, qf[sub], zero4);         // S^T tile
      float p0 = exp2f(fmaxf(sv.x * t2l, 0.f));
      float p1 = exp2f(fmaxf(sv.y * t2l, 0.f));
      float p2 = exp2f(fmaxf(sv.z * t2l, 0.f));
      float p3 = exp2f(fmaxf(sv.w * t2l, 0.f));
      la[sub] += (p0 + p1) + (p2 + p3);
      unsigned int lo = (__float_as_uint(p0) >> 16) | (__float_as_uint(p1) & 0xFFFF0000u);
      unsigned int hi = (__float_as_uint(p2) >> 16) | (__float_as_uint(p3) & 0xFFFF0000u);
      uint2 pu = make_uint2(lo, hi);
      bf16x4 pf = *(bf16x4*)&pu;
      oacc[sub] = mfma16(vf, pf, oacc[sub]);         // outs^T += V * P
    }
  }

  size_t base = (size_t)bh * SPLIT + s;
#pragma unroll
  for (int sub = 0; sub < 4; sub++) {
    float lv = la[sub];
    lv += __shfl_xor(lv, 16);
    lv += __shfl_xor(lv, 32);
    int q = qt * 64 + sub * 16 + ql;
    spl_o[(base * 16 + 4 * g + 0) * NPIX + q] = oacc[sub].x;
    spl_o[(base * 16 + 4 * g + 1) * NPIX + q] = oacc[sub].y;
    spl_o[(base * 16 + 4 * g + 2) * NPIX + q] = oacc[sub].z;
    spl_o[(base * 16 + 4 * g + 3) * NPIX + q] = oacc[sub].w;
    if (g == 0) spl_l[base * NPIX + q] = lv;
  }
}

// ---------------- combine spatial partials: outs = (sum_s o) / (sum_s l) ----------------
// thread per (bh,n,ch-half); grid 6*4096*2/64 = 768 blocks
__global__ __launch_bounds__(64) void sp_combine_kernel(
    const float* __restrict__ spl_o, const float* __restrict__ spl_l,
    float* __restrict__ outs)
{
  int gid = blockIdx.x * 64 + threadIdx.x;
  int n = gid & (NPIX - 1);
  int rest = gid >> 12;          // 0..11
  int cg = rest & 1, bh = rest >> 1;
  int b = bh / 3, h = bh % 3;
  float l = 0.f;
#pragma unroll
  for (int s = 0; s < SPLIT; s++) l += spl_l[((size_t)bh * SPLIT + s) * NPIX + n];
  float inv = 1.f / l;
#pragma unroll
  for (int c0 = 0; c0 < 8; c0++) {
    int c = cg * 8 + c0;
    float o = 0.f;
#pragma unroll
    for (int s = 0; s < SPLIT; s++)
      o += spl_o[(((size_t)bh * SPLIT + s) * 16 + c) * NPIX + n];
    outs[(size_t)(b * 48 + h * 16 + c) * NPIX + n] = o * inv;
  }
}

// ---------------- project outc/outs + residual -> y ----------------
// grid: B*(N/64)*8 (o-split 8) = 1024 blocks, block 64
__global__ __launch_bounds__(64) void proj_kernel(
    const float* __restrict__ inp, const float* __restrict__ outc,
    const float* __restrict__ outs, const float* __restrict__ po1_w,
    const float* __restrict__ po1_b, const float* __restrict__ po2_w,
    const float* __restrict__ po2_b, const float* __restrict__ beta,
    const float* __restrict__ beta2, float* __restrict__ y_ws)
{
  int bid = blockIdx.x;
  int os = bid & 7; bid >>= 3;
  int b = bid >> 6;
  int n = ((bid & 63) << 6) + threadIdx.x;
  float oc[48], ov[48];
  const float* pc = outc + (size_t)b * 48 * NPIX;
  const float* ps = outs + (size_t)b * 48 * NPIX;
#pragma unroll
  for (int c = 0; c < 48; c++) { oc[c] = pc[c * NPIX + n]; ov[c] = ps[c * NPIX + n]; }
  for (int o = os * 6; o < os * 6 + 6; o++) {
    const float* w1 = po1_w + o * 48;
    const float* w2 = po2_w + o * 48;
    float a1 = 0.f, a2 = 0.f;
#pragma unroll
    for (int c = 0; c < 48; c++) { a1 += w1[c] * oc[c]; a2 += w2[c] * ov[c]; }
    float yv = inp[(size_t)(b * 48 + o) * NPIX + n]
             + (a1 + po1_b[o]) * beta[o] + (a2 + po2_b[o]) * beta2[o];
    y_ws[(size_t)(b * 48 + o) * NPIX + n] = yv;
  }
}

// ---------------- LN2 + GLU FFN + residual -> out ----------------
// grid: B*(N/32) = 256 blocks, 256 threads: 32 px x 8 j-groups, LDS reduce
__global__ __launch_bounds__(256) void ffn_kernel(
    const float* __restrict__ y_ws, const float* __restrict__ conv4_w,
    const float* __restrict__ conv4_b, const float* __restrict__ conv5_w,
    const float* __restrict__ conv5_b, const float* __restrict__ ln2_w,
    const float* __restrict__ ln2_b, const float* __restrict__ gamma,
    float* __restrict__ outp)
{
  int bid = blockIdx.x;
  int b = bid >> 7;
  int n0 = (bid & 127) << 5;
  int tid = threadIdx.x;
  int p = tid & 31, jg = tid >> 5;
  int n = n0 + p;
  const float* src = y_ws + (size_t)b * 48 * NPIX;

  float t[48];
  float mu = 0.f;
#pragma unroll
  for (int c = 0; c < 48; c++) { t[c] = src[c * NPIX + n]; mu += t[c]; }
  mu *= (1.f / 48.f);
  float var = 0.f;
#pragma unroll
  for (int c = 0; c < 48; c++) { float d = t[c] - mu; var += d * d; }
  var *= (1.f / 48.f);
  float rstd = 1.f / sqrtf(var + 1e-6f);
#pragma unroll
  for (int c = 0; c < 48; c++) t[c] = (t[c] - mu) * rstd * ln2_w[c] + ln2_b[c];

  float fa[48];
#pragma unroll
  for (int o = 0; o < 48; o++) fa[o] = 0.f;
  for (int j = jg * 6; j < jg * 6 + 6; j++) {
    const float* w4a = conv4_w + j * 48;
    const float* w4b = conv4_w + (j + 48) * 48;
    float g1 = conv4_b[j], g2 = conv4_b[j + 48];
#pragma unroll
    for (int c = 0; c < 48; c++) { g1 += w4a[c] * t[c]; g2 += w4b[c] * t[c]; }
    float hh = g1 * g2;
#pragma unroll
    for (int o = 0; o < 48; o++) fa[o] += conv5_w[o * 48 + j] * hh;
  }

  __shared__ float part[8][32][49];
#pragma unroll
  for (int o = 0; o < 48; o++) part[jg][p][o] = fa[o];
  __syncthreads();
#pragma unroll
  for (int oo = 0; oo < 6; oo++) {
    int o = jg * 6 + oo;
    float sum = 0.f;
#pragma unroll
    for (int g = 0; g < 8; g++) sum += part[g][p][o];
    outp[(size_t)(b * 48 + o) * NPIX + n] =
        src[o * NPIX + n] + (sum + conv5_b[o]) * gamma[o];
  }
}

extern "C" void kernel_launch(void* const* d_in, const int* in_sizes, int n_in,
                              void* d_out, int out_size, void* d_ws, size_t ws_size,
                              hipStream_t stream)
{
  (void)in_sizes; (void)n_in; (void)out_size; (void)ws_size;
  const float* inp     = (const float*)d_in[0];
  const float* qkv_w   = (const float*)d_in[1];
  const float* qkv_b   = (const float*)d_in[2];
  const float* dw_w    = (const float*)d_in[3];
  const float* dw_b    = (const float*)d_in[4];
  const float* po1_w   = (const float*)d_in[5];
  const float* po1_b   = (const float*)d_in[6];
  const float* po2_w   = (const float*)d_in[7];
  const float* po2_b   = (const float*)d_in[8];
  const float* temp1   = (const float*)d_in[9];
  const float* temp2   = (const float*)d_in[10];
  const float* conv4_w = (const float*)d_in[11];
  const float* conv4_b = (const float*)d_in[12];
  const float* conv5_w = (const float*)d_in[13];
  const float* conv5_b = (const float*)d_in[14];
  const float* ln1_w   = (const float*)d_in[15];
  const float* ln1_b   = (const float*)d_in[16];
  const float* ln2_w   = (const float*)d_in[17];
  const float* ln2_b   = (const float*)d_in[18];
  const float* beta    = (const float*)d_in[19];
  const float* beta2   = (const float*)d_in[20];
  const float* gamma   = (const float*)d_in[21];
  float* out = (float*)d_out;

  float* ws      = (float*)d_ws;
  float* t_buf   = ws;                 // dead after dwconv
  float* spl_l   = ws;                 // overlays t_buf
  float* cd_norm = ws + 196608;
  float* cd_dot  = ws + 208896;
  u16*   Vb      = (u16*)(ws + 307200);   // live prep..spattn (ends 503808)
  float* outs    = ws + 307200;           // written after spattn (ends 700416)
  u16*   Qb      = (u16*)(ws + 700416);   // ends 897024
  u16*   Kb      = (u16*)(ws + 897024);   // ends 1093632 < 1179648
  float* qkvb    = ws + 1179648;
  float* outc    = ws + 2359296;
  float* y_ws    = ws + 2752512;
  float* spl_o   = ws + 3145728;
  // total ws use: 6,291,456 floats (25.2 MB)

  // 1) LN1 + qkv 1x1 conv
  ln_qkv_kernel<<<2 * 64 * 16, 64, 0, stream>>>(inp, qkv_w, qkv_b, ln1_w, ln1_b, t_buf);
  // 2) depthwise 3x3
  dwconv_kernel<<<(2 * 144 * NPIX) / 256, 256, 0, stream>>>(t_buf, dw_w, dw_b, qkvb);
  // 3) prep: normalize q,k + bf16 conversion of q,k,v
  prep_bf16_kernel<<<384, 256, 0, stream>>>(qkvb, Qb, Kb, Vb);
  // 4a) channel attention: partial norms + dots
  chattn_dots_kernel<<<384, 256, 0, stream>>>(qkvb, cd_norm, cd_dot);
  // 4b) channel attention: softmax + PV
  chattn_pv_kernel<<<384, 128, 0, stream>>>(qkvb, cd_norm, cd_dot, temp1, outc);
  // 5) spatial attention (bf16 MFMA flash, split-m)
  spattn_kernel<<<6 * SPLIT * 64, 64, 0, stream>>>(Qb, Kb, Vb, temp2, spl_o, spl_l);
  // 6) combine spatial partials
  sp_combine_kernel<<<768, 64, 0, stream>>>(spl_o, spl_l, outs);
  // 7) output projections + residual
  proj_kernel<<<2 * 64 * 8, 64, 0, stream>>>(inp, outc, outs, po1_w, po1_b,
                                             po2_w, po2_b, beta, beta2, y_ws);
  // 8) LN2 + GLU FFN + residual
  ffn_kernel<<<2 * 128, 256, 0, stream>>>(y_ws, conv4_w, conv4_b, conv5_w, conv5_b,
                                          ln2_w, ln2_b, gamma, out);
}